// Round 2
// baseline (3071.418 us; speedup 1.0000x reference)
//
#include <hip/hip_runtime.h>
#include <hip/hip_bf16.h>

// Problem geometry
#define HWF 128     // feature H=W
#define NB  64      // B*N rois (batch of the conv stack)
#define PW  30      // padded plane width  (28 + 2)
#define PP  900     // padded plane elems  (30*30)

using bf16 = __hip_bfloat16;

__device__ __forceinline__ float b2f(bf16 v) { return __bfloat162float(v); }
__device__ __forceinline__ bf16  f2b(float v){ return __float2bfloat16(v); }

// ---------------------------------------------------------------------------
// Fold (deconv2x2s2 -> 1x1 conv) into W_eff[k=ky*2+kx][o=0..2][ci] + b_eff[o]
// o=0: hm head; o=1,2: wh head channels 0,1
// Semantics of conv_transpose(transpose_kernel=True, 'IOHW'):
//   y[co, 2t+ky, 2s+kx] = sum_ci x[ci,t,s] * dw[co, ci, ky, kx]   (dim0 = OUT)
// => W_eff[k][o][ci] = sum_co head_w[o][co] * dw[co*1024 + ci*4 + k]
// ---------------------------------------------------------------------------
__global__ void weff_kernel(const float* __restrict__ hm_dw, const float* __restrict__ hm_db,
                            const float* __restrict__ hm_w,  const float* __restrict__ hm_b,
                            const float* __restrict__ wh_dw, const float* __restrict__ wh_db,
                            const float* __restrict__ wh_w,  const float* __restrict__ wh_b,
                            float* __restrict__ Weff, float* __restrict__ beff) {
  const int blk = blockIdx.x;          // 0..11 == k*3 + o
  const int k = blk / 3, o = blk % 3;  // k = ky*2+kx
  const int ci = threadIdx.x;          // 0..255
  const float* dw = (o == 0) ? hm_dw : wh_dw;
  const float* hw = (o == 0) ? hm_w  : (wh_w + (size_t)(o - 1) * 256);
  const float* dwp = dw + (size_t)ci * 4 + k;   // dw[co][ci][k] = co*1024 + ci*4 + k
  float s = 0.f;
  for (int co = 0; co < 256; ++co) s += hw[co] * dwp[(size_t)co * 1024];
  Weff[(size_t)blk * 256 + ci] = s;
  if (k == 0 && ci == 0) {
    const float* db = (o == 0) ? hm_db : wh_db;
    float bb = (o == 0) ? hm_b[0] : wh_b[o - 1];
    float t = 0.f;
    for (int co = 0; co < 256; ++co) t += hw[co] * db[co];
    beff[o] = bb + t;
  }
}

// ---------------------------------------------------------------------------
// ROI align -> padded bf16 (64 rois, 64 ch, 30, 30); borders zeroed here.
// grid (64 rois, 8 channel-groups of 8)
// ---------------------------------------------------------------------------
__global__ __launch_bounds__(256) void roi_kernel(const float* __restrict__ feat,
                                                  const int* __restrict__ act_ind,
                                                  const float* __restrict__ awh,
                                                  bf16* __restrict__ roiP) {
  const int r = blockIdx.x;        // roi 0..63
  const int cblk = blockIdx.y;     // 0..7 (8 channels each)
  const int b = r >> 5;            // roi // 32
  const int t = threadIdx.x;
  __shared__ int   sx0[56], sx1[56], sy0[56], sy1[56];
  __shared__ float swx[56], swy[56];
  if (t < 56) {
    int ind = act_ind[r];
    float cx = (float)(ind % HWF), cy = (float)(ind / HWF);
    float hw = awh[r * 2 + 0] * 0.5f, hh = awh[r * 2 + 1] * 0.5f;
    float f  = (float)t * 0.5f + 0.25f;
    float xc = (cx - hw) + f * (2.f * hw / 28.f);
    xc = fminf(fmaxf(xc, 0.f), 127.f);
    int x0 = (int)floorf(xc);
    sx0[t] = x0; sx1[t] = min(x0 + 1, 127); swx[t] = xc - (float)x0;
    float yc = (cy - hh) + f * (2.f * hh / 28.f);
    yc = fminf(fmaxf(yc, 0.f), 127.f);
    int y0 = (int)floorf(yc);
    sy0[t] = y0; sy1[t] = min(y0 + 1, 127); swy[t] = yc - (float)y0;
  }
  __syncthreads();
  const float* img = feat + ((size_t)b * 64 + (size_t)cblk * 8) * (HWF * HWF);
  bf16* ob = roiP + ((size_t)r * 64 + (size_t)cblk * 8) * PP;
  for (int idx = t; idx < 8 * 784; idx += 256) {
    int c = idx / 784, p = idx % 784;
    int ry = p / 28, rx = p % 28;
    const float* pc = img + (size_t)c * (HWF * HWF);
    float s = 0.f;
#pragma unroll
    for (int a = 0; a < 2; ++a) {
      int sy = 2 * ry + a;
      int y0 = sy0[sy], y1 = sy1[sy];
      float wy = swy[sy];
#pragma unroll
      for (int b2 = 0; b2 < 2; ++b2) {
        int sxx = 2 * rx + b2;
        int x0 = sx0[sxx], x1 = sx1[sxx];
        float wx = swx[sxx];
        float v00 = pc[y0 * HWF + x0], v01 = pc[y0 * HWF + x1];
        float v10 = pc[y1 * HWF + x0], v11 = pc[y1 * HWF + x1];
        float r0 = v00 * (1.f - wy) + v10 * wy;
        float r1 = v01 * (1.f - wy) + v11 * wy;
        s += r0 * (1.f - wx) + r1 * wx;
      }
    }
    ob[(size_t)c * PP + (ry + 1) * PW + (rx + 1)] = f2b(s * 0.25f);
  }
  // zero the 116 border positions of each of this block's 8 planes
  for (int idx = t; idx < 8 * 116; idx += 256) {
    int c = idx / 116, j = idx % 116;
    int py, px;
    if (j < 30)      { py = 0;      px = j;      }
    else if (j < 60) { py = 29;     px = j - 30; }
    else if (j < 88) { py = j - 59; px = 0;      }
    else             { py = j - 87; px = 29;     }
    ob[(size_t)c * PP + py * PW + px] = f2b(0.f);
  }
}

// ---------------------------------------------------------------------------
// 3x3 SAME conv + bias + ReLU, padded bf16 in -> padded bf16 out (256 out ch)
// grid (64 images, 32 co-groups of 8), block 256. 4 pixels/thread.
// Weights fp32, read via wave-uniform indices (scalar loads).
// ---------------------------------------------------------------------------
template <int CIN>
__global__ __launch_bounds__(256) void conv3x3(const bf16* __restrict__ in,
                                               const float* __restrict__ w,
                                               const float* __restrict__ bias,
                                               bf16* __restrict__ out) {
  const int b = blockIdx.x;
  const int cob = blockIdx.y;   // 8 output channels per block
  const int t = threadIdx.x;
  const bf16* inb = in + (size_t)b * CIN * PP;

  int  pj[4], off[4];
  bool fresh[4];
#pragma unroll
  for (int j = 0; j < 4; ++j) {
    int p = t + j * 256;
    fresh[j] = (p < 784);
    if (p > 783) p = 783;
    pj[j] = p;
    int py = p / 28 + 1, px = p % 28 + 1;
    off[j] = (py - 1) * PW + (px - 1);
  }

  float acc[8][4];
#pragma unroll
  for (int co = 0; co < 8; ++co) {
    float bv = bias[cob * 8 + co];
#pragma unroll
    for (int j = 0; j < 4; ++j) acc[co][j] = bv;
  }

  const float* wbase = w + (size_t)(cob * 8) * CIN * 9;
  for (int ci = 0; ci < CIN; ++ci) {
    float T[4][9];
#pragma unroll
    for (int j = 0; j < 4; ++j) {
      const bf16* ip = inb + (size_t)ci * PP + off[j];
#pragma unroll
      for (int ky = 0; ky < 3; ++ky)
#pragma unroll
        for (int kx = 0; kx < 3; ++kx)
          T[j][ky * 3 + kx] = b2f(ip[ky * PW + kx]);
    }
#pragma unroll
    for (int co = 0; co < 8; ++co) {
      const float* wr = wbase + ((size_t)co * CIN + ci) * 9;
      float w0 = wr[0], w1 = wr[1], w2 = wr[2], w3 = wr[3], w4 = wr[4];
      float w5 = wr[5], w6 = wr[6], w7 = wr[7], w8 = wr[8];
#pragma unroll
      for (int j = 0; j < 4; ++j) {
        acc[co][j] += T[j][0] * w0 + T[j][1] * w1 + T[j][2] * w2
                    + T[j][3] * w3 + T[j][4] * w4 + T[j][5] * w5
                    + T[j][6] * w6 + T[j][7] * w7 + T[j][8] * w8;
      }
    }
  }

#pragma unroll
  for (int j = 0; j < 4; ++j) {
    if (!fresh[j]) continue;
    int p = pj[j];
    int py = p / 28 + 1, px = p % 28 + 1;
#pragma unroll
    for (int co = 0; co < 8; ++co) {
      size_t ob = ((size_t)(b * 256 + cob * 8 + co)) * PP + (size_t)py * PW;
      out[ob + px] = f2b(fmaxf(acc[co][j], 0.f));
      if (px == 1)  out[ob + 0]  = f2b(0.f);
      if (px == 28) out[ob + 29] = f2b(0.f);
    }
  }
}

// ---------------------------------------------------------------------------
// Fused head: for each input pixel, 12 dots of length 256 -> out (64,3,56,56)
// ---------------------------------------------------------------------------
__global__ __launch_bounds__(256) void head_kernel(const bf16* __restrict__ x,
                                                   const float* __restrict__ Weff,
                                                   const float* __restrict__ beff,
                                                   float* __restrict__ out) {
  const int b = blockIdx.x;
  const int t = threadIdx.x;
  const bf16* xb = x + (size_t)b * 256 * PP;

  int  pj[4], off[4];
  bool fresh[4];
#pragma unroll
  for (int j = 0; j < 4; ++j) {
    int p = t + j * 256;
    fresh[j] = (p < 784);
    if (p > 783) p = 783;
    pj[j] = p;
    int iy = p / 28, ix = p % 28;
    off[j] = (iy + 1) * PW + (ix + 1);
  }

  float acc[12][4];
#pragma unroll
  for (int ko = 0; ko < 12; ++ko)
#pragma unroll
    for (int j = 0; j < 4; ++j) acc[ko][j] = 0.f;

  for (int ci = 0; ci < 256; ++ci) {
    float v[4];
#pragma unroll
    for (int j = 0; j < 4; ++j) v[j] = b2f(xb[(size_t)ci * PP + off[j]]);
#pragma unroll
    for (int ko = 0; ko < 12; ++ko) {
      float wv = Weff[(size_t)ko * 256 + ci];
#pragma unroll
      for (int j = 0; j < 4; ++j) acc[ko][j] += v[j] * wv;
    }
  }

  float bo[3] = { beff[0], beff[1], beff[2] };
#pragma unroll
  for (int j = 0; j < 4; ++j) {
    if (!fresh[j]) continue;
    int p = pj[j];
    int iy = p / 28, ix = p % 28;
#pragma unroll
    for (int k = 0; k < 4; ++k) {
      int oy = 2 * iy + (k >> 1), ox = 2 * ix + (k & 1);
#pragma unroll
      for (int o = 0; o < 3; ++o) {
        out[(((size_t)(b * 3 + o)) * 56 + oy) * 56 + ox] = acc[k * 3 + o][j] + bo[o];
      }
    }
  }
}

// ---------------------------------------------------------------------------
extern "C" void kernel_launch(void* const* d_in, const int* in_sizes, int n_in,
                              void* d_out, int out_size, void* d_ws, size_t ws_size,
                              hipStream_t stream) {
  const float* feat    = (const float*)d_in[0];
  const int*   act_ind = (const int*)  d_in[1];
  const float* awh     = (const float*)d_in[2];
  const float* w1 = (const float*)d_in[3];  const float* b1 = (const float*)d_in[4];
  const float* w2 = (const float*)d_in[5];  const float* b2 = (const float*)d_in[6];
  const float* w3 = (const float*)d_in[7];  const float* b3 = (const float*)d_in[8];
  const float* w4 = (const float*)d_in[9];  const float* b4 = (const float*)d_in[10];
  const float* hm_dw = (const float*)d_in[11]; const float* hm_db = (const float*)d_in[12];
  const float* hm_w  = (const float*)d_in[13]; const float* hm_b  = (const float*)d_in[14];
  const float* wh_dw = (const float*)d_in[15]; const float* wh_db = (const float*)d_in[16];
  const float* wh_w  = (const float*)d_in[17]; const float* wh_b  = (const float*)d_in[18];

  char* ws = (char*)d_ws;
  size_t offset = 0;
  auto alloc = [&](size_t bytes) {
    size_t r = offset;
    offset += (bytes + 255) & ~(size_t)255;
    return r;
  };
  float* Weff = (float*)(ws + alloc(12 * 256 * sizeof(float)));
  float* beff = (float*)(ws + alloc(256));
  bf16*  roiP = (bf16*)(ws + alloc((size_t)NB * 64  * PP * sizeof(bf16)));
  bf16*  bufA = (bf16*)(ws + alloc((size_t)NB * 256 * PP * sizeof(bf16)));
  bf16*  bufB = (bf16*)(ws + alloc((size_t)NB * 256 * PP * sizeof(bf16)));

  // zero both activation buffers (gives the zero row-borders the convs rely on)
  hipMemsetAsync(bufA, 0, (size_t)NB * 256 * PP * sizeof(bf16), stream);
  hipMemsetAsync(bufB, 0, (size_t)NB * 256 * PP * sizeof(bf16), stream);

  weff_kernel<<<12, 256, 0, stream>>>(hm_dw, hm_db, hm_w, hm_b,
                                      wh_dw, wh_db, wh_w, wh_b, Weff, beff);
  roi_kernel<<<dim3(NB, 8), 256, 0, stream>>>(feat, act_ind, awh, roiP);
  conv3x3<64> <<<dim3(NB, 32), 256, 0, stream>>>(roiP, w1, b1, bufA);
  conv3x3<256><<<dim3(NB, 32), 256, 0, stream>>>(bufA, w2, b2, bufB);
  conv3x3<256><<<dim3(NB, 32), 256, 0, stream>>>(bufB, w3, b3, bufA);
  conv3x3<256><<<dim3(NB, 32), 256, 0, stream>>>(bufA, w4, b4, bufB);
  head_kernel<<<NB, 256, 0, stream>>>(bufB, Weff, beff, (float*)d_out);
}

// Round 3
// 783.691 us; speedup vs baseline: 3.9192x; 3.9192x over previous
//
#include <hip/hip_runtime.h>
#include <hip/hip_bf16.h>

#define HWF 128
#define NB  64
#define PW  30
#define PP  900

using bf16 = __hip_bfloat16;
typedef __attribute__((ext_vector_type(8))) short short8;
typedef __attribute__((ext_vector_type(4))) float f32x4;

__device__ __forceinline__ float b2f(bf16 v) { return __bfloat162float(v); }
__device__ __forceinline__ bf16  f2b(float v){ return __float2bfloat16(v); }
__device__ __forceinline__ float u2f(unsigned short u){ unsigned x = (unsigned)u << 16; float f; __builtin_memcpy(&f,&x,4); return f; }
__device__ __forceinline__ unsigned pack2(float a, float b) {
  union { bf16 h; unsigned short u; } ca, cb; ca.h = f2b(a); cb.h = f2b(b);
  return ((unsigned)cb.u << 16) | (unsigned)ca.u;
}

// ---------------------------------------------------------------------------
// Head fold: W_eff[k=ky*2+kx][o][ci] = sum_co head_w[o][co] * dw[co][ci][ky][kx]
// ---------------------------------------------------------------------------
__global__ void weff_kernel(const float* __restrict__ hm_dw, const float* __restrict__ hm_db,
                            const float* __restrict__ hm_w,  const float* __restrict__ hm_b,
                            const float* __restrict__ wh_dw, const float* __restrict__ wh_db,
                            const float* __restrict__ wh_w,  const float* __restrict__ wh_b,
                            float* __restrict__ Weff, float* __restrict__ beff) {
  const int blk = blockIdx.x;          // 0..11 == k*3 + o
  const int k = blk / 3, o = blk % 3;
  const int ci = threadIdx.x;
  const float* dw = (o == 0) ? hm_dw : wh_dw;
  const float* hw = (o == 0) ? hm_w  : (wh_w + (size_t)(o - 1) * 256);
  const float* dwp = dw + (size_t)ci * 4 + k;
  float s = 0.f;
  for (int co = 0; co < 256; ++co) s += hw[co] * dwp[(size_t)co * 1024];
  Weff[(size_t)blk * 256 + ci] = s;
  if (k == 0 && ci == 0) {
    const float* db = (o == 0) ? hm_db : wh_db;
    float bb = (o == 0) ? hm_b[0] : wh_b[o - 1];
    float t = 0.f;
    for (int co = 0; co < 256; ++co) t += hw[co] * db[co];
    beff[o] = bb + t;
  }
}

// ---------------------------------------------------------------------------
// Weight transform: w[co][ci][3][3] fp32 -> Wt[tap][co][ci] bf16
// ---------------------------------------------------------------------------
__global__ void wt_kernel(const float* __restrict__ w, bf16* __restrict__ Wt, int CIN) {
  const int co = blockIdx.x, ci = threadIdx.x;
  for (int tap = 0; tap < 9; ++tap)
    Wt[((size_t)tap * 256 + co) * CIN + ci] = f2b(w[((size_t)co * CIN + ci) * 9 + tap]);
}

// ---------------------------------------------------------------------------
// Feature transpose: feat[b][64][128][128] fp32 -> featT[b][y][x][64] bf16
// ---------------------------------------------------------------------------
__global__ __launch_bounds__(256) void featT_kernel(const float* __restrict__ feat,
                                                    bf16* __restrict__ featT) {
  const int by = blockIdx.x;           // b*128 + y
  const int b = by >> 7, y = by & 127;
  const int t = threadIdx.x;
  __shared__ float tile[4][64];
  for (int x0 = 0; x0 < 128; x0 += 4) {
    int c = t >> 2, xx = t & 3;
    tile[xx][c] = feat[(((size_t)(b * 64 + c) * 128 + y) * 128) + x0 + xx];
    __syncthreads();
    int xo = t >> 6, cc = t & 63;
    featT[(((size_t)by * 128) + x0 + xo) * 64 + cc] = f2b(tile[xo][cc]);
    __syncthreads();
  }
}

// ---------------------------------------------------------------------------
// ROI align channel-last: featT -> roiP[roi][900][64] bf16 (borders zeroed)
// grid (64, 8): y<7 = 112-pixel strips (wave per pixel, lane=channel); y==7 borders
// ---------------------------------------------------------------------------
__global__ __launch_bounds__(256) void roi_cl(const bf16* __restrict__ featT,
                                              const int* __restrict__ act_ind,
                                              const float* __restrict__ awh,
                                              bf16* __restrict__ roiP) {
  const int r = blockIdx.x, part = blockIdx.y;
  const int t = threadIdx.x;
  if (part == 7) {
    for (int i = t; i < 116 * 64; i += 256) {
      int j = i >> 6, c = i & 63;
      int py, px;
      if (j < 30)      { py = 0;      px = j;      }
      else if (j < 60) { py = 29;     px = j - 30; }
      else if (j < 88) { py = j - 59; px = 0;      }
      else             { py = j - 87; px = 29;     }
      roiP[((size_t)r * PP + py * PW + px) * 64 + c] = f2b(0.f);
    }
    return;
  }
  const int wave = t >> 6, c = t & 63;
  const int bi = r >> 5;
  const int ind = act_ind[r];
  const float cx = (float)(ind % HWF), cy = (float)(ind / HWF);
  const float hw = awh[r * 2 + 0] * 0.5f, hh = awh[r * 2 + 1] * 0.5f;
  const float x1b = cx - hw, y1b = cy - hh;
  const float bw = hw / 14.f, bh = hh / 14.f;
  const bf16* fb = featT + (size_t)bi * HWF * HWF * 64;
  for (int pp = part * 112 + wave; pp < part * 112 + 112; pp += 4) {
    int ry = pp / 28, rx = pp % 28;
    float acc = 0.f;
#pragma unroll
    for (int a = 0; a < 2; ++a) {
      int syi = 2 * ry + a;
      float ys = y1b + ((float)syi * 0.5f + 0.25f) * bh;
      ys = fminf(fmaxf(ys, 0.f), 127.f);
      int y0 = (int)floorf(ys); int y1i = min(y0 + 1, 127);
      float wy = ys - (float)y0;
#pragma unroll
      for (int b2 = 0; b2 < 2; ++b2) {
        int sxi = 2 * rx + b2;
        float xs = x1b + ((float)sxi * 0.5f + 0.25f) * bw;
        xs = fminf(fmaxf(xs, 0.f), 127.f);
        int x0 = (int)floorf(xs); int x1i = min(x0 + 1, 127);
        float wx = xs - (float)x0;
        float v00 = b2f(fb[((size_t)y0  * HWF + x0 ) * 64 + c]);
        float v01 = b2f(fb[((size_t)y0  * HWF + x1i) * 64 + c]);
        float v10 = b2f(fb[((size_t)y1i * HWF + x0 ) * 64 + c]);
        float v11 = b2f(fb[((size_t)y1i * HWF + x1i) * 64 + c]);
        float r0 = v00 * (1.f - wy) + v10 * wy;
        float r1 = v01 * (1.f - wy) + v11 * wy;
        acc += r0 * (1.f - wx) + r1 * wx;
      }
    }
    roiP[((size_t)r * PP + (ry + 1) * PW + (rx + 1)) * 64 + c] = f2b(acc * 0.25f);
  }
}

// ---------------------------------------------------------------------------
// MFMA implicit-GEMM conv3x3 + bias + ReLU, channel-last.
// X [64][900][CIN] bf16, Wt [9][256][CIN] bf16, Y [64][900][256] bf16.
// grid (64 img, 7 strips of 4 output rows), block 256 (4 waves).
// Wave w: co 64w..64w+63 (4 M-frags) x 112 pixels (7 N-frags).
// LDS: double-buffered 192x[32ci] tile, slot-rotated for bank conflicts.
// ---------------------------------------------------------------------------
template <int CIN>
__global__ __launch_bounds__(256, 2) void conv_mfma(const bf16* __restrict__ X,
                                                    const bf16* __restrict__ Wt,
                                                    const float* __restrict__ bias,
                                                    bf16* __restrict__ Y) {
  constexpr int NCIB = CIN / 32;
  const int img = blockIdx.x;
  const int strip = blockIdx.y;
  const int t = threadIdx.x;
  const int wave = t >> 6;
  const int lane = t & 63;
  const int g = lane >> 4;          // k-group (8 ci per group)
  const int lr = lane & 15;         // row/col within fragment
  const int wco = wave * 64;

  __shared__ char lds[2][192 * 64];

  const bf16* Xb = X + (size_t)(img * PP + strip * 120) * CIN;

  int tp0[7];
#pragma unroll
  for (int n = 0; n < 7; ++n) {
    int p = n * 16 + lr;
    tp0[n] = p + 2 * (p / 28);      // (r)*30 + c with r=p/28,c=p%28
  }

  f32x4 acc[4][7];
#pragma unroll
  for (int m = 0; m < 4; ++m)
#pragma unroll
    for (int n = 0; n < 7; ++n) acc[m][n] = f32x4{0.f, 0.f, 0.f, 0.f};

  // staging: 12 x 1KB issues; wave w owns issues 3w..3w+2.
  // linear LDS slot (tpix, slin) holds src ci-slot (slin - (tpix>>1))&3
  // so read with slot' = (g + (tpix>>1))&3 retrieves ci-group g.
#define STAGE(BUF, CI0)                                                          \
  {                                                                              \
    _Pragma("unroll")                                                            \
    for (int ii = 0; ii < 3; ++ii) {                                             \
      int issue = wave * 3 + ii;                                                 \
      int tpix = (issue * 64 + lane) >> 2;                                       \
      int tpc = tpix > 179 ? 179 : tpix;                                         \
      int sslot = ((lane & 3) - (tpix >> 1)) & 3;                                \
      const bf16* src = Xb + (size_t)tpc * CIN + (CI0) + sslot * 8;              \
      char* dst = &lds[(BUF)][issue * 1024];                                     \
      __builtin_amdgcn_global_load_lds(                                          \
          (const __attribute__((address_space(1))) unsigned int*)src,            \
          (__attribute__((address_space(3))) unsigned int*)dst, 16, 0, 0);       \
    }                                                                            \
  }

  STAGE(0, 0);
  __syncthreads();

  for (int cib = 0; cib < NCIB; ++cib) {
    const int buf = cib & 1;
    if (cib + 1 < NCIB) STAGE(buf ^ 1, (cib + 1) * 32);
    const int ci0 = cib * 32;
    const char* lb = &lds[buf][0];
#pragma unroll
    for (int tap = 0; tap < 9; ++tap) {
      const int dt = (tap / 3) * 30 + (tap % 3);
      short8 a[4];
#pragma unroll
      for (int m = 0; m < 4; ++m) {
        int co = wco + m * 16 + lr;
        a[m] = *(const short8*)(Wt + ((size_t)(tap * 256 + co) * CIN + ci0 + g * 8));
      }
      short8 bfr[7];
#pragma unroll
      for (int n = 0; n < 7; ++n) {
        int tp = tp0[n] + dt;
        int addr = tp * 64 + (((g + (tp >> 1)) & 3) << 4);
        bfr[n] = *(const short8*)(lb + addr);
      }
#pragma unroll
      for (int m = 0; m < 4; ++m)
#pragma unroll
        for (int n = 0; n < 7; ++n)
          acc[m][n] = __builtin_amdgcn_mfma_f32_16x16x32_bf16(a[m], bfr[n], acc[m][n], 0, 0, 0);
    }
    __syncthreads();
  }

  // epilogue: bias + ReLU, bf16x4 packed stores, border maintenance
  f32x4 bv[4];
#pragma unroll
  for (int m = 0; m < 4; ++m)
    bv[m] = *(const f32x4*)(bias + wco + m * 16 + g * 4);

  bf16* Yb = Y + (size_t)img * PP * 256;
#pragma unroll
  for (int n = 0; n < 7; ++n) {
    int p = n * 16 + lr;
    int Rr = p / 28, Cc = p % 28;
    size_t rowoff = (size_t)((strip * 4 + Rr + 1) * PW) * 256;
#pragma unroll
    for (int m = 0; m < 4; ++m) {
      int co0 = wco + m * 16 + g * 4;
      f32x4 v = acc[m][n];
      float r0 = fmaxf(v[0] + bv[m][0], 0.f), r1 = fmaxf(v[1] + bv[m][1], 0.f);
      float r2 = fmaxf(v[2] + bv[m][2], 0.f), r3 = fmaxf(v[3] + bv[m][3], 0.f);
      uint2 pk; pk.x = pack2(r0, r1); pk.y = pack2(r2, r3);
      *(uint2*)(Yb + rowoff + (size_t)(Cc + 1) * 256 + co0) = pk;
      uint2 z; z.x = 0u; z.y = 0u;
      if (Cc == 0)  *(uint2*)(Yb + rowoff + co0) = z;
      if (Cc == 27) *(uint2*)(Yb + rowoff + (size_t)29 * 256 + co0) = z;
    }
  }
  if (strip == 0 || strip == 6) {
    size_t rowbase = (strip == 0) ? 0 : (size_t)29 * PW * 0 + 870; // 29*30=870
    for (int i = t; i < 30 * 64; i += 256) {
      int px = i >> 6, c4 = (i & 63) << 2;
      uint2 z; z.x = 0u; z.y = 0u;
      *(uint2*)(Yb + (rowbase + px) * 256 + c4) = z;
    }
  }
}

// ---------------------------------------------------------------------------
// Head: 12 dots of length 256 per pixel -> out (64,3,56,56) fp32
// ---------------------------------------------------------------------------
__global__ __launch_bounds__(256) void head_cl(const bf16* __restrict__ X,
                                               const float* __restrict__ Weff,
                                               const float* __restrict__ beff,
                                               float* __restrict__ out) {
  const int img = blockIdx.x, t = threadIdx.x;
  const float bo0 = beff[0], bo1 = beff[1], bo2 = beff[2];
  for (int p = t; p < 784; p += 256) {
    int iy = p / 28, ix = p % 28;
    const bf16* xp = X + ((size_t)img * PP + (iy + 1) * PW + ix + 1) * 256;
    float acc[12];
#pragma unroll
    for (int k = 0; k < 12; ++k) acc[k] = 0.f;
    for (int c8 = 0; c8 < 32; ++c8) {
      short8 v = *(const short8*)(xp + c8 * 8);
#pragma unroll
      for (int j = 0; j < 8; ++j) {
        float xv = u2f((unsigned short)v[j]);
#pragma unroll
        for (int k = 0; k < 12; ++k)
          acc[k] += xv * Weff[k * 256 + c8 * 8 + j];
      }
    }
#pragma unroll
    for (int k4 = 0; k4 < 4; ++k4) {
      int oy = 2 * iy + (k4 >> 1), ox = 2 * ix + (k4 & 1);
      out[(((size_t)(img * 3 + 0)) * 56 + oy) * 56 + ox] = acc[k4 * 3 + 0] + bo0;
      out[(((size_t)(img * 3 + 1)) * 56 + oy) * 56 + ox] = acc[k4 * 3 + 1] + bo1;
      out[(((size_t)(img * 3 + 2)) * 56 + oy) * 56 + ox] = acc[k4 * 3 + 2] + bo2;
    }
  }
}

// ---------------------------------------------------------------------------
extern "C" void kernel_launch(void* const* d_in, const int* in_sizes, int n_in,
                              void* d_out, int out_size, void* d_ws, size_t ws_size,
                              hipStream_t stream) {
  const float* feat    = (const float*)d_in[0];
  const int*   act_ind = (const int*)  d_in[1];
  const float* awh     = (const float*)d_in[2];
  const float* w1 = (const float*)d_in[3];  const float* b1 = (const float*)d_in[4];
  const float* w2 = (const float*)d_in[5];  const float* b2 = (const float*)d_in[6];
  const float* w3 = (const float*)d_in[7];  const float* b3 = (const float*)d_in[8];
  const float* w4 = (const float*)d_in[9];  const float* b4 = (const float*)d_in[10];
  const float* hm_dw = (const float*)d_in[11]; const float* hm_db = (const float*)d_in[12];
  const float* hm_w  = (const float*)d_in[13]; const float* hm_b  = (const float*)d_in[14];
  const float* wh_dw = (const float*)d_in[15]; const float* wh_db = (const float*)d_in[16];
  const float* wh_w  = (const float*)d_in[17]; const float* wh_b  = (const float*)d_in[18];

  char* ws = (char*)d_ws;
  size_t offset = 0;
  auto alloc = [&](size_t bytes) {
    size_t r = offset;
    offset += (bytes + 255) & ~(size_t)255;
    return r;
  };
  float* Weff = (float*)(ws + alloc(12 * 256 * sizeof(float)));
  float* beff = (float*)(ws + alloc(256));
  bf16*  Wt1  = (bf16*)(ws + alloc((size_t)9 * 256 * 64  * 2));
  bf16*  Wt2  = (bf16*)(ws + alloc((size_t)9 * 256 * 256 * 2));
  bf16*  Wt3  = (bf16*)(ws + alloc((size_t)9 * 256 * 256 * 2));
  bf16*  Wt4  = (bf16*)(ws + alloc((size_t)9 * 256 * 256 * 2));
  bf16*  bufA = (bf16*)(ws + alloc((size_t)NB * 256 * PP * 2));
  bf16*  bufB = (bf16*)(ws + alloc((size_t)NB * 256 * PP * 2));
  // aliases inside bufB (dead before conv2 writes bufB):
  bf16*  roiP  = bufB;                                   // 7.37 MB
  bf16*  featT = (bf16*)((char*)bufB + (8u << 20));      // 4.19 MB at +8MB

  weff_kernel<<<12, 256, 0, stream>>>(hm_dw, hm_db, hm_w, hm_b,
                                      wh_dw, wh_db, wh_w, wh_b, Weff, beff);
  wt_kernel<<<256, 64,  0, stream>>>(w1, Wt1, 64);
  wt_kernel<<<256, 256, 0, stream>>>(w2, Wt2, 256);
  wt_kernel<<<256, 256, 0, stream>>>(w3, Wt3, 256);
  wt_kernel<<<256, 256, 0, stream>>>(w4, Wt4, 256);
  featT_kernel<<<256, 256, 0, stream>>>(feat, featT);
  roi_cl<<<dim3(NB, 8), 256, 0, stream>>>(featT, act_ind, awh, roiP);
  conv_mfma<64> <<<dim3(NB, 7), 256, 0, stream>>>(roiP, Wt1, b1, bufA);
  conv_mfma<256><<<dim3(NB, 7), 256, 0, stream>>>(bufA, Wt2, b2, bufB);
  conv_mfma<256><<<dim3(NB, 7), 256, 0, stream>>>(bufB, Wt3, b3, bufA);
  conv_mfma<256><<<dim3(NB, 7), 256, 0, stream>>>(bufA, Wt4, b4, bufB);
  head_cl<<<NB, 256, 0, stream>>>(bufB, Weff, beff, (float*)d_out);
}

// Round 4
// 723.092 us; speedup vs baseline: 4.2476x; 1.0838x over previous
//
#include <hip/hip_runtime.h>
#include <hip/hip_bf16.h>

#define HWF 128
#define NB  64
#define PW  30
#define PP  900

using bf16 = __hip_bfloat16;
typedef __attribute__((ext_vector_type(8))) short short8;
typedef __attribute__((ext_vector_type(4))) float f32x4;

__device__ __forceinline__ float b2f(bf16 v) { return __bfloat162float(v); }
__device__ __forceinline__ bf16  f2b(float v){ return __float2bfloat16(v); }
__device__ __forceinline__ float u2f(unsigned short u){ unsigned x = (unsigned)u << 16; float f; __builtin_memcpy(&f,&x,4); return f; }
__device__ __forceinline__ unsigned pack2(float a, float b) {
  union { bf16 h; unsigned short u; } ca, cb; ca.h = f2b(a); cb.h = f2b(b);
  return ((unsigned)cb.u << 16) | (unsigned)ca.u;
}

// ---------------------------------------------------------------------------
// Head fold: W_eff[k=ky*2+kx][o][ci] = sum_co head_w[o][co] * dw[co][ci][ky][kx]
// ---------------------------------------------------------------------------
__global__ void weff_kernel(const float* __restrict__ hm_dw, const float* __restrict__ hm_db,
                            const float* __restrict__ hm_w,  const float* __restrict__ hm_b,
                            const float* __restrict__ wh_dw, const float* __restrict__ wh_db,
                            const float* __restrict__ wh_w,  const float* __restrict__ wh_b,
                            float* __restrict__ Weff, float* __restrict__ beff) {
  const int blk = blockIdx.x;          // 0..11 == k*3 + o
  const int k = blk / 3, o = blk % 3;
  const int ci = threadIdx.x;
  const float* dw = (o == 0) ? hm_dw : wh_dw;
  const float* hw = (o == 0) ? hm_w  : (wh_w + (size_t)(o - 1) * 256);
  const float* dwp = dw + (size_t)ci * 4 + k;
  float s = 0.f;
  for (int co = 0; co < 256; ++co) s += hw[co] * dwp[(size_t)co * 1024];
  Weff[(size_t)blk * 256 + ci] = s;
  if (k == 0 && ci == 0) {
    const float* db = (o == 0) ? hm_db : wh_db;
    float bb = (o == 0) ? hm_b[0] : wh_b[o - 1];
    float t = 0.f;
    for (int co = 0; co < 256; ++co) t += hw[co] * db[co];
    beff[o] = bb + t;
  }
}

// ---------------------------------------------------------------------------
// Weight transform: w[co][ci][3][3] fp32 -> Wt[tap][cib][co][g][8ci] bf16
// (a wave's per-m load = contiguous 1KB)
// ---------------------------------------------------------------------------
__global__ void wt_kernel(const float* __restrict__ w, bf16* __restrict__ Wt, int CIN) {
  const int co = blockIdx.x, ci = threadIdx.x;
  const int NCIB = CIN >> 5;
  const int cib = ci >> 5, g = (ci >> 3) & 3, e = ci & 7;
  for (int tap = 0; tap < 9; ++tap)
    Wt[((((size_t)tap * NCIB + cib) * 256 + co) * 4 + g) * 8 + e]
        = f2b(w[((size_t)co * CIN + ci) * 9 + tap]);
}

// ---------------------------------------------------------------------------
// Feature transpose: feat[b][64][128][128] fp32 -> featT[b][y][x][64] bf16
// LDS transpose: coalesced x-major reads, c-major writes.
// ---------------------------------------------------------------------------
__global__ __launch_bounds__(256) void featT_kernel(const float* __restrict__ feat,
                                                    bf16* __restrict__ featT) {
  const int by = blockIdx.x;           // b*128 + y
  const int b = by >> 7, y = by & 127;
  const int t = threadIdx.x;
  __shared__ float tile[128][65];
  const int xr = t & 127, c2 = t >> 7;           // read: lane-major x
  for (int c0 = 0; c0 < 64; c0 += 2)
    tile[xr][c0 + c2] = feat[(((size_t)(b * 64 + c0 + c2) * 128 + y) * 128) + xr];
  __syncthreads();
  const int cw = t & 63, x4 = t >> 6;            // write: lane-major c
  for (int x0 = 0; x0 < 128; x0 += 4)
    featT[(((size_t)by * 128) + x0 + x4) * 64 + cw] = f2b(tile[x0 + x4][cw]);
}

// ---------------------------------------------------------------------------
// ROI align channel-last: featT -> roiP[roi][900][64] bf16 (borders zeroed)
// ---------------------------------------------------------------------------
__global__ __launch_bounds__(256) void roi_cl(const bf16* __restrict__ featT,
                                              const int* __restrict__ act_ind,
                                              const float* __restrict__ awh,
                                              bf16* __restrict__ roiP) {
  const int r = blockIdx.x, part = blockIdx.y;
  const int t = threadIdx.x;
  if (part == 7) {
    for (int i = t; i < 116 * 64; i += 256) {
      int j = i >> 6, c = i & 63;
      int py, px;
      if (j < 30)      { py = 0;      px = j;      }
      else if (j < 60) { py = 29;     px = j - 30; }
      else if (j < 88) { py = j - 59; px = 0;      }
      else             { py = j - 87; px = 29;     }
      roiP[((size_t)r * PP + py * PW + px) * 64 + c] = f2b(0.f);
    }
    return;
  }
  const int wave = t >> 6, c = t & 63;
  const int bi = r >> 5;
  const int ind = act_ind[r];
  const float cx = (float)(ind % HWF), cy = (float)(ind / HWF);
  const float hw = awh[r * 2 + 0] * 0.5f, hh = awh[r * 2 + 1] * 0.5f;
  const float x1b = cx - hw, y1b = cy - hh;
  const float bw = hw / 14.f, bh = hh / 14.f;
  const bf16* fb = featT + (size_t)bi * HWF * HWF * 64;
  for (int pp = part * 112 + wave; pp < part * 112 + 112; pp += 4) {
    int ry = pp / 28, rx = pp % 28;
    float acc = 0.f;
#pragma unroll
    for (int a = 0; a < 2; ++a) {
      int syi = 2 * ry + a;
      float ys = y1b + ((float)syi * 0.5f + 0.25f) * bh;
      ys = fminf(fmaxf(ys, 0.f), 127.f);
      int y0 = (int)floorf(ys); int y1i = min(y0 + 1, 127);
      float wy = ys - (float)y0;
#pragma unroll
      for (int b2 = 0; b2 < 2; ++b2) {
        int sxi = 2 * rx + b2;
        float xs = x1b + ((float)sxi * 0.5f + 0.25f) * bw;
        xs = fminf(fmaxf(xs, 0.f), 127.f);
        int x0 = (int)floorf(xs); int x1i = min(x0 + 1, 127);
        float wx = xs - (float)x0;
        float v00 = b2f(fb[((size_t)y0  * HWF + x0 ) * 64 + c]);
        float v01 = b2f(fb[((size_t)y0  * HWF + x1i) * 64 + c]);
        float v10 = b2f(fb[((size_t)y1i * HWF + x0 ) * 64 + c]);
        float v11 = b2f(fb[((size_t)y1i * HWF + x1i) * 64 + c]);
        float r0 = v00 * (1.f - wy) + v10 * wy;
        float r1 = v01 * (1.f - wy) + v11 * wy;
        acc += r0 * (1.f - wx) + r1 * wx;
      }
    }
    roiP[((size_t)r * PP + (ry + 1) * PW + (rx + 1)) * 64 + c] = f2b(acc * 0.25f);
  }
}

// ---------------------------------------------------------------------------
// MFMA implicit-GEMM conv3x3 + bias + ReLU, channel-last.
// X [64][900][CIN] bf16, Wt [9][NCIB][256][4][8] bf16, Y [64][900][256] bf16.
// grid (64 img, 7 strips of 4 output rows), block 512 (8 waves).
// Wave w: co 32w..32w+31 (2 M-frags) x 112 pixels (7 N-frags).
// LDS: double-buffered 192x[32ci] tile, slot-rotated for bank conflicts;
// staged ONCE per block via global_load_lds width-16.
// ---------------------------------------------------------------------------
template <int CIN>
__global__ __launch_bounds__(512, 4) void conv_mfma(const bf16* __restrict__ X,
                                                    const bf16* __restrict__ Wt,
                                                    const float* __restrict__ bias,
                                                    bf16* __restrict__ Y) {
  constexpr int NCIB = CIN / 32;
  const int img = blockIdx.x;
  const int strip = blockIdx.y;
  const int t = threadIdx.x;
  const int wave = t >> 6;
  const int lane = t & 63;
  const int g = lane >> 4;          // k-group (8 ci per group)
  const int lr = lane & 15;         // row/col within fragment
  const int wco = wave * 32;

  __shared__ char lds[2][192 * 64];

  const bf16* Xb = X + (size_t)(img * PP + strip * 120) * CIN;

  int tp0[7];
#pragma unroll
  for (int n = 0; n < 7; ++n) {
    int p = n * 16 + lr;
    tp0[n] = p + 2 * (p / 28);      // r*30 + c
  }

  f32x4 acc[2][7];
#pragma unroll
  for (int m = 0; m < 2; ++m)
#pragma unroll
    for (int n = 0; n < 7; ++n) acc[m][n] = f32x4{0.f, 0.f, 0.f, 0.f};

  // 12 x 1KB staging issues split over 8 waves (waves 0-3 take 2, 4-7 take 1)
#define STAGE(BUF, CI0)                                                          \
  {                                                                              \
    _Pragma("unroll")                                                            \
    for (int ii = 0; ii < 2; ++ii) {                                             \
      int issue = wave + 8 * ii;                                                 \
      if (issue < 12) {                                                          \
        int tpix = (issue * 64 + lane) >> 2;                                     \
        int tpc = tpix > 179 ? 179 : tpix;                                       \
        int sslot = ((lane & 3) - (tpix >> 1)) & 3;                              \
        const bf16* src = Xb + (size_t)tpc * CIN + (CI0) + sslot * 8;            \
        char* dst = &lds[(BUF)][issue * 1024];                                   \
        __builtin_amdgcn_global_load_lds(                                        \
            (const __attribute__((address_space(1))) unsigned int*)src,          \
            (__attribute__((address_space(3))) unsigned int*)dst, 16, 0, 0);     \
      }                                                                          \
    }                                                                            \
  }

  STAGE(0, 0);
  __syncthreads();

  for (int cib = 0; cib < NCIB; ++cib) {
    const int buf = cib & 1;
    if (cib + 1 < NCIB) STAGE(buf ^ 1, (cib + 1) * 32);
    const char* lb = &lds[buf][0];
    const bf16* wb = Wt + (size_t)cib * 256 * 32;
#pragma unroll
    for (int tap = 0; tap < 9; ++tap) {
      const int dt = (tap / 3) * 30 + (tap % 3);
      const bf16* wt = wb + (size_t)tap * NCIB * 256 * 32;
      short8 a[2];
#pragma unroll
      for (int m = 0; m < 2; ++m) {
        int co = wco + m * 16 + lr;
        a[m] = *(const short8*)(wt + ((size_t)co * 4 + g) * 8);
      }
      short8 bfr[7];
#pragma unroll
      for (int n = 0; n < 7; ++n) {
        int tp = tp0[n] + dt;
        int addr = tp * 64 + (((g + (tp >> 1)) & 3) << 4);
        bfr[n] = *(const short8*)(lb + addr);
      }
#pragma unroll
      for (int m = 0; m < 2; ++m)
#pragma unroll
        for (int n = 0; n < 7; ++n)
          acc[m][n] = __builtin_amdgcn_mfma_f32_16x16x32_bf16(a[m], bfr[n], acc[m][n], 0, 0, 0);
    }
    __syncthreads();
  }

  // epilogue: bias + ReLU, bf16x4 packed stores, border maintenance
  f32x4 bv[2];
#pragma unroll
  for (int m = 0; m < 2; ++m)
    bv[m] = *(const f32x4*)(bias + wco + m * 16 + g * 4);

  bf16* Yb = Y + (size_t)img * PP * 256;
#pragma unroll
  for (int n = 0; n < 7; ++n) {
    int p = n * 16 + lr;
    int Rr = p / 28, Cc = p % 28;
    size_t rowoff = (size_t)((strip * 4 + Rr + 1) * PW) * 256;
#pragma unroll
    for (int m = 0; m < 2; ++m) {
      int co0 = wco + m * 16 + g * 4;
      f32x4 v = acc[m][n];
      float r0 = fmaxf(v[0] + bv[m][0], 0.f), r1 = fmaxf(v[1] + bv[m][1], 0.f);
      float r2 = fmaxf(v[2] + bv[m][2], 0.f), r3 = fmaxf(v[3] + bv[m][3], 0.f);
      uint2 pk; pk.x = pack2(r0, r1); pk.y = pack2(r2, r3);
      *(uint2*)(Yb + rowoff + (size_t)(Cc + 1) * 256 + co0) = pk;
      uint2 z; z.x = 0u; z.y = 0u;
      if (Cc == 0)  *(uint2*)(Yb + rowoff + co0) = z;
      if (Cc == 27) *(uint2*)(Yb + rowoff + (size_t)29 * 256 + co0) = z;
    }
  }
  if (strip == 0 || strip == 6) {
    size_t rowbase = (strip == 0) ? 0 : (size_t)870;   // row 0 / row 29 (29*30)
    for (int i = t; i < 30 * 64; i += 512) {
      int px = i >> 6, c4 = (i & 63) << 2;
      uint2 z; z.x = 0u; z.y = 0u;
      *(uint2*)(Yb + (rowbase + px) * 256 + c4) = z;
    }
  }
}

// ---------------------------------------------------------------------------
// Head: 12 dots of length 256 per pixel -> out (64,3,56,56) fp32
// ---------------------------------------------------------------------------
__global__ __launch_bounds__(256) void head_cl(const bf16* __restrict__ X,
                                               const float* __restrict__ Weff,
                                               const float* __restrict__ beff,
                                               float* __restrict__ out) {
  const int img = blockIdx.x, t = threadIdx.x;
  const float bo0 = beff[0], bo1 = beff[1], bo2 = beff[2];
  for (int p = t; p < 784; p += 256) {
    int iy = p / 28, ix = p % 28;
    const bf16* xp = X + ((size_t)img * PP + (iy + 1) * PW + ix + 1) * 256;
    float acc[12];
#pragma unroll
    for (int k = 0; k < 12; ++k) acc[k] = 0.f;
    for (int c8 = 0; c8 < 32; ++c8) {
      short8 v = *(const short8*)(xp + c8 * 8);
#pragma unroll
      for (int j = 0; j < 8; ++j) {
        float xv = u2f((unsigned short)v[j]);
#pragma unroll
        for (int k = 0; k < 12; ++k)
          acc[k] += xv * Weff[k * 256 + c8 * 8 + j];
      }
    }
#pragma unroll
    for (int k4 = 0; k4 < 4; ++k4) {
      int oy = 2 * iy + (k4 >> 1), ox = 2 * ix + (k4 & 1);
      out[(((size_t)(img * 3 + 0)) * 56 + oy) * 56 + ox] = acc[k4 * 3 + 0] + bo0;
      out[(((size_t)(img * 3 + 1)) * 56 + oy) * 56 + ox] = acc[k4 * 3 + 1] + bo1;
      out[(((size_t)(img * 3 + 2)) * 56 + oy) * 56 + ox] = acc[k4 * 3 + 2] + bo2;
    }
  }
}

// ---------------------------------------------------------------------------
extern "C" void kernel_launch(void* const* d_in, const int* in_sizes, int n_in,
                              void* d_out, int out_size, void* d_ws, size_t ws_size,
                              hipStream_t stream) {
  const float* feat    = (const float*)d_in[0];
  const int*   act_ind = (const int*)  d_in[1];
  const float* awh     = (const float*)d_in[2];
  const float* w1 = (const float*)d_in[3];  const float* b1 = (const float*)d_in[4];
  const float* w2 = (const float*)d_in[5];  const float* b2 = (const float*)d_in[6];
  const float* w3 = (const float*)d_in[7];  const float* b3 = (const float*)d_in[8];
  const float* w4 = (const float*)d_in[9];  const float* b4 = (const float*)d_in[10];
  const float* hm_dw = (const float*)d_in[11]; const float* hm_db = (const float*)d_in[12];
  const float* hm_w  = (const float*)d_in[13]; const float* hm_b  = (const float*)d_in[14];
  const float* wh_dw = (const float*)d_in[15]; const float* wh_db = (const float*)d_in[16];
  const float* wh_w  = (const float*)d_in[17]; const float* wh_b  = (const float*)d_in[18];

  char* ws = (char*)d_ws;
  size_t offset = 0;
  auto alloc = [&](size_t bytes) {
    size_t r = offset;
    offset += (bytes + 255) & ~(size_t)255;
    return r;
  };
  float* Weff = (float*)(ws + alloc(12 * 256 * sizeof(float)));
  float* beff = (float*)(ws + alloc(256));
  bf16*  Wt1  = (bf16*)(ws + alloc((size_t)9 * 256 * 64  * 2));
  bf16*  Wt2  = (bf16*)(ws + alloc((size_t)9 * 256 * 256 * 2));
  bf16*  Wt3  = (bf16*)(ws + alloc((size_t)9 * 256 * 256 * 2));
  bf16*  Wt4  = (bf16*)(ws + alloc((size_t)9 * 256 * 256 * 2));
  bf16*  bufA = (bf16*)(ws + alloc((size_t)NB * 256 * PP * 2));
  bf16*  bufB = (bf16*)(ws + alloc((size_t)NB * 256 * PP * 2));
  // aliases inside bufB (dead before conv2 writes bufB):
  bf16*  roiP  = bufB;                                   // 7.37 MB
  bf16*  featT = (bf16*)((char*)bufB + (8u << 20));      // 4.19 MB at +8MB

  weff_kernel<<<12, 256, 0, stream>>>(hm_dw, hm_db, hm_w, hm_b,
                                      wh_dw, wh_db, wh_w, wh_b, Weff, beff);
  wt_kernel<<<256, 64,  0, stream>>>(w1, Wt1, 64);
  wt_kernel<<<256, 256, 0, stream>>>(w2, Wt2, 256);
  wt_kernel<<<256, 256, 0, stream>>>(w3, Wt3, 256);
  wt_kernel<<<256, 256, 0, stream>>>(w4, Wt4, 256);
  featT_kernel<<<256, 256, 0, stream>>>(feat, featT);
  roi_cl<<<dim3(NB, 8), 256, 0, stream>>>(featT, act_ind, awh, roiP);
  conv_mfma<64> <<<dim3(NB, 7), 512, 0, stream>>>(roiP, Wt1, b1, bufA);
  conv_mfma<256><<<dim3(NB, 7), 512, 0, stream>>>(bufA, Wt2, b2, bufB);
  conv_mfma<256><<<dim3(NB, 7), 512, 0, stream>>>(bufB, Wt3, b3, bufA);
  conv_mfma<256><<<dim3(NB, 7), 512, 0, stream>>>(bufA, Wt4, b4, bufB);
  head_cl<<<NB, 256, 0, stream>>>(bufB, Weff, beff, (float*)d_out);
}